// Round 7
// baseline (233.729 us; speedup 1.0000x reference)
//
#include <hip/hip_runtime.h>
#include <hip/hip_bf16.h>

typedef __attribute__((ext_vector_type(8))) __bf16 bf16x8;
typedef __attribute__((ext_vector_type(4))) __bf16 bf16x4;
typedef __attribute__((ext_vector_type(4))) float f32x4;

constexpr int M = 16384;
constexpr int K = 512;
constexpr int BK = 32;
constexpr int NT = 16;       // K / BK

__device__ __forceinline__ void async_copy16(const void* gsrc, void* ldst) {
  __builtin_amdgcn_global_load_lds(
      (const __attribute__((address_space(1))) unsigned int*)(gsrc),
      (__attribute__((address_space(3))) unsigned int*)(ldst),
      16, 0, 0);
}

__device__ __forceinline__ float frcp(float x) { return __builtin_amdgcn_rcpf(x); }
__device__ __forceinline__ float ftanh(float x) {
  return 1.0f - 2.0f * frcp(1.0f + __expf(2.0f * x));
}
__device__ __forceinline__ float fsigm(float x) { return frcp(1.0f + __expf(-x)); }

// Epilogue scratch swizzle (R4-proven): row stride 128 els (256B, bank-
// aligned); per-row XOR on the 8-el chunk gives the 4 kc row-groups distinct
// shifts -> stores 2-way max (free), reads cover each row once.
__device__ __forceinline__ int kswz(int row) {
  return ((row & 3) << 3) ^ ((row & 12) << 2);
}

// ---------------------------------------------------------------------------
// R7: geometry change only; R6's proven sync structure kept byte-for-byte.
// R6 POST-MORTEM: counted-vmcnt alone nulled (MODE2/3 unchanged) - consistent
// with the regime gate (T4 pays only with phase-split; 4-wave lockstep).
// The real cap: at 4x4 per-wave blocking, LDS reads cost 0.5KB/MFMA ~ 6cyc
// vs MFMA 4.85cyc -> LDS pipe structurally slower than matrix pipe.
// FIX: 256x128 tile, 4 waves 2Mx2N, wave-tile 128x64 (8x4 frags) -> LDS
// 0.375KB/MFMA (~4.4cyc < 4.85): matrix pipe becomes the long pole.
// Per CU (2 blocks): 256 MFMA ~ 1242cyc vs LDS ~ 1129cyc per K-step.
// Swizzle math invariant: sw=(fr>>1)&3 unchanged (wm,mi*16 are == 0 mod 4
// after >>1); staging scol XOR identical, r-loop extended to 4 for A.
// acc 8x4 f32x4 = 128 VGPR, peak live ~205 -> launch_bounds(256) +
// amdgpu_waves_per_eu(2) pins the 256-VGPR budget (2 waves/SIMD = 2
// blocks/CU, which 72KB LDS forces anyway). SPILL WATCH: VGPR_Count==128
// with WRITE_SIZE >> 50MB means the allocator ignored us -> revert.
// Dispatches: cvt_all | L1 (3 nets, 768 blk) | L2 (3 nets incl z, 768 blk)
// | final (R0-proven streaming combine). z stored tanh'd (R0 numerics).
// NOTE: never runtime-index acc[]/frag arrays (scratch spill lesson).
// ---------------------------------------------------------------------------
template <int MODE>   // 1: a1 = tanh(hx@W1^T+b1); 2: gates = act(a1@W2^T+b2)
__global__ __launch_bounds__(256)
__attribute__((amdgpu_waves_per_eu(2))) void gemm_kernel(
    const __bf16* __restrict__ Ab,     // MODE1: hxb [M][512]; MODE2: a1 [3][M][512]
    const __bf16* __restrict__ W,      // [3][512][512] bf16 (N,K) row-major
    const float* __restrict__ bias,    // [7][512] fp32
    __bf16* __restrict__ outb)         // MODE1: a1; MODE2: gates [3][M][512]
{
  const int jj = blockIdx.z;
  const int mbase = blockIdx.x * 256;
  const int nbase = blockIdx.y * 128;
  constexpr size_t NH = (size_t)M * 512;

  const __bf16* Aj = (MODE == 1) ? Ab : Ab + (size_t)jj * NH;
  const __bf16* Wj = W + (size_t)jj * 262144;
  const int brow = 2 * jj + 1;                // bias row: i2=1, f2=3, z=5

  // 3 staging buffers x (As 8192 + Bs 4096) = 36864 el = 72 KB.
  // Epilogue scratch reuses els [0..32767] ([256][128], kswz'd).
  __shared__ __align__(16) __bf16 smem[36864];

  const int tid  = threadIdx.x;
  const int wid  = tid >> 6;
  const int lane = tid & 63;
  const int wm   = (wid >> 1) * 128;          // wave M-offset (0|128)
  const int wn   = (wid & 1) * 64;            // wave N-offset (0|64)
  const int srow = wid * 16 + (lane >> 2);
  const int scol = ((lane & 3) ^ ((lane >> 3) & 3)) * 8;  // swizzled src chunk
  const int fr   = lane & 15;
  const int kc   = lane >> 4;
  const int sw   = (fr >> 1) & 3;
  const int rowq = kc * 4;

  auto stage = [&](int p, int k0) {
    __bf16* As = smem + p * 12288;
    __bf16* Bs = As + 8192;
#pragma unroll
    for (int r = 0; r < 4; ++r)     // A: 256 rows
      async_copy16(Aj + (size_t)(mbase + r * 64 + srow) * K + (k0 + scol),
                   (void*)&As[(r * 64 + wid * 16) * BK]);
#pragma unroll
    for (int r = 0; r < 2; ++r)     // B: 128 rows
      async_copy16(Wj + (size_t)(nbase + r * 64 + srow) * K + (k0 + scol),
                   (void*)&Bs[(r * 64 + wid * 16) * BK]);
  };

  f32x4 acc[8][4] = {};

  stage(0, 0);
  stage(1, BK);
  int pr = 0, ps = 2;
  for (int t = 0; t < NT; ++t) {
    // ONE waitcnt: retire this wave's ds_reads (lgkmcnt 0) AND everything
    // but the newest stage (6 copies) BEFORE the barrier; tile t+2's copies
    // stay in flight across it (never drain to 0 mid-loop).
    if (t < NT - 2) asm volatile("s_waitcnt vmcnt(6) lgkmcnt(0)" ::: "memory");
    else            asm volatile("s_waitcnt vmcnt(0) lgkmcnt(0)" ::: "memory");
    __builtin_amdgcn_s_barrier();
    __builtin_amdgcn_sched_barrier(0);   // rule #18: pin code below the bar
    if (t < NT - 2) stage(ps, (t + 2) * BK);

    const __bf16* As = smem + pr * 12288;
    const __bf16* Bs = As + 8192;
    bf16x8 af[8], bfr[4];
#pragma unroll
    for (int i = 0; i < 8; ++i)
      af[i]  = *(const bf16x8*)&As[(wm + i * 16 + fr) * BK + ((kc ^ sw) * 8)];
#pragma unroll
    for (int i = 0; i < 4; ++i)
      bfr[i] = *(const bf16x8*)&Bs[(wn + i * 16 + fr) * BK + ((kc ^ sw) * 8)];
#pragma unroll
    for (int mi = 0; mi < 8; ++mi)
#pragma unroll
      for (int ni = 0; ni < 4; ++ni)
        acc[mi][ni] = __builtin_amdgcn_mfma_f32_16x16x32_bf16(
            af[mi], bfr[ni], acc[mi][ni], 0, 0, 0);

    pr = (pr == 2) ? 0 : pr + 1;
    ps = (ps == 2) ? 0 : ps + 1;
  }

  // Epilogue. C/D layout: col=fr, row=rowq+r.
  float bv[4];
  const float* bj = bias + (size_t)brow * 512 + nbase + wn;
#pragma unroll
  for (int ni = 0; ni < 4; ++ni) bv[ni] = bj[ni * 16 + fr];

  __syncthreads();  // full drain; smem reusable as C scratch
#pragma unroll
  for (int mi = 0; mi < 8; ++mi)
#pragma unroll
    for (int ni = 0; ni < 4; ++ni)
#pragma unroll
      for (int r = 0; r < 4; ++r) {
        float v = acc[mi][ni][r] + bv[ni];
        float res;
        if constexpr (MODE == 1) res = ftanh(v);
        else res = (jj == 2) ? ftanh(fsigm(ftanh(v)))   // z, stored tanh'd
                             : fsigm(ftanh(v));         // i2 / f2
        const int row = wm + mi * 16 + rowq + r;        // 0..255
        const int col = wn + ni * 16 + fr;              // 0..127
        smem[row * 128 + (col ^ kswz(row))] = (__bf16)res;
      }
  __syncthreads();
#pragma unroll
  for (int it = 0; it < 16; ++it) {
    const int s = it * 256 + tid;   // 0..4095
    const int row = s >> 4, ch = s & 15;
    bf16x8 v = *(const bf16x8*)&smem[row * 128 + ((ch * 8) ^ kswz(row))];
    *(bf16x8*)&outb[(size_t)jj * NH + (size_t)(mbase + row) * 512 +
                    (nbase + ch * 8)] = v;
  }
}

// cy2 = f2*cx2 + i2*z   gates = [i2 | f2 | z(tanh'd)] bf16 [3][M][512]
// (R0-proven streaming kernel)
__global__ __launch_bounds__(256) void final_kernel(
    const __bf16* __restrict__ gates, const float* __restrict__ cx2,
    float* __restrict__ out)
{
  constexpr size_t NH = (size_t)M * 512;
  const size_t i = ((size_t)blockIdx.x * 256 + threadIdx.x) * 8;
  bf16x8 i2 = *(const bf16x8*)&gates[i];
  bf16x8 f2 = *(const bf16x8*)&gates[NH + i];
  bf16x8 zz = *(const bf16x8*)&gates[2 * NH + i];
  f32x4 c0 = *(const f32x4*)&cx2[i];
  f32x4 c1 = *(const f32x4*)&cx2[i + 4];
#pragma unroll
  for (int h = 0; h < 2; ++h) {
    f32x4 r;
#pragma unroll
    for (int q = 0; q < 4; ++q) {
      const int e = h * 4 + q;
      r[q] = (float)f2[e] * (h ? c1[q] : c0[q]) + (float)i2[e] * (float)zz[e];
    }
    *(f32x4*)&out[i + h * 4] = r;
  }
}

// One conversion dispatch: blocks [0,1536) pick rows 2y+1 of W1/W2
// ([7][512][512] fp32) -> Wb [6][512][512] bf16; blocks [1536,9728) convert
// hx [M][512] fp32 -> hxb bf16.
__global__ __launch_bounds__(256) void cvt_all(const float* __restrict__ hx,
                                               const float* __restrict__ W1,
                                               const float* __restrict__ W2,
                                               __bf16* __restrict__ hxb,
                                               __bf16* __restrict__ Wb) {
  const int b = blockIdx.x;
  if (b < 1536) {
    const int y = b >> 8;          // 0..5
    const int bb = b & 255;
    const float* src = (y < 3) ? W1 + (size_t)(2 * y + 1) * 262144
                               : W2 + (size_t)(2 * (y - 3) + 1) * 262144;
    __bf16* d = Wb + (size_t)y * 262144;
    const size_t i = ((size_t)bb * 256 + threadIdx.x) * 4;
    f32x4 v = *(const f32x4*)&src[i];
    *(bf16x4*)&d[i] = __builtin_convertvector(v, bf16x4);
  } else {
    const size_t i = ((size_t)(b - 1536) * 256 + threadIdx.x) * 4;
    f32x4 v = *(const f32x4*)&hx[i];
    *(bf16x4*)&hxb[i] = __builtin_convertvector(v, bf16x4);
  }
}

extern "C" void kernel_launch(void* const* d_in, const int* in_sizes, int n_in,
                              void* d_out, int out_size, void* d_ws, size_t ws_size,
                              hipStream_t stream) {
  const float* hx  = (const float*)d_in[0];
  // d_in[1] = cx1 (dead: cy1 is never returned)
  const float* cx2 = (const float*)d_in[2];
  const float* W1  = (const float*)d_in[3];
  const float* b1  = (const float*)d_in[4];
  const float* W2  = (const float*)d_in[5];
  const float* b2  = (const float*)d_in[6];
  float* out = (float*)d_out;

  // ws: Wb @0 (3MB) | hxb @3MB (16MB) | a1 @19922944 (48MB) |
  //     gates @70254592 (48MB: i2,f2,z) -> ~115MB
  char* ws = (char*)d_ws;
  __bf16* Wb    = (__bf16*)(ws);
  __bf16* hxb   = (__bf16*)(ws + 3145728);
  __bf16* a1    = (__bf16*)(ws + 19922944);
  __bf16* gates = (__bf16*)(ws + 70254592);
  __bf16* W2b   = Wb + 3 * 262144;

  cvt_all<<<9728, 256, 0, stream>>>(hx, W1, W2, hxb, Wb);

  // layer 1 (3 nets): 64x4x3 = 768 blocks @ 2/CU -> 1.5 rounds
  gemm_kernel<1><<<dim3(64, 4, 3), 256, 0, stream>>>(hxb, Wb, b1, a1);
  // layer 2 (3 nets incl z): 768 blocks
  gemm_kernel<2><<<dim3(64, 4, 3), 256, 0, stream>>>(a1, W2b, b2, gates);
  // combine
  final_kernel<<<4096, 256, 0, stream>>>(gates, cx2, out);
}